// Round 1
// baseline (459.145 us; speedup 1.0000x reference)
//
#include <hip/hip_runtime.h>
#include <hip/hip_bf16.h>

#define B_ 4
#define I_ 512
#define J_ 512
#define C_ 512
#define P_ 128
#define H_ 4
#define D_ 32
#define HD_ 128
#define EPS_ 1e-5f
#define INF_ 1.0e9f

__device__ __forceinline__ float dot4(float4 a, float4 b) {
    return a.x * b.x + a.y * b.y + a.z * b.z + a.w * b.w;
}

// ---------------------------------------------------------------------------
// K1: LayerNorm of node_embed_i and node_embed_j. One wave (64 lanes) per row,
// 8 floats per lane (2x float4), butterfly reduce over 64 lanes.
// grid: (B*I/4, 2), block: 256
// ---------------------------------------------------------------------------
__global__ __launch_bounds__(256) void k_ln_nodes(
    const float* __restrict__ xi, const float* __restrict__ xj,
    const float* __restrict__ g_i, const float* __restrict__ b_i,
    const float* __restrict__ g_j, const float* __restrict__ b_j,
    float* __restrict__ ni, float* __restrict__ nj)
{
    const int which = blockIdx.y;
    const float* x  = which ? xj  : xi;
    const float* gg = which ? g_j : g_i;
    const float* bb = which ? b_j : b_i;
    float* o        = which ? nj  : ni;

    const int row  = blockIdx.x * 4 + (threadIdx.x >> 6);
    const int lane = threadIdx.x & 63;

    const float* xr = x + (size_t)row * C_ + lane * 8;
    float4 v0 = *(const float4*)xr;
    float4 v1 = *(const float4*)(xr + 4);

    float s  = v0.x + v0.y + v0.z + v0.w + v1.x + v1.y + v1.z + v1.w;
    float sq = v0.x*v0.x + v0.y*v0.y + v0.z*v0.z + v0.w*v0.w
             + v1.x*v1.x + v1.y*v1.y + v1.z*v1.z + v1.w*v1.w;
#pragma unroll
    for (int m = 1; m <= 32; m <<= 1) {
        s  += __shfl_xor(s, m);
        sq += __shfl_xor(sq, m);
    }
    const float mean = s * (1.0f / C_);
    const float var  = sq * (1.0f / C_) - mean * mean;
    const float rstd = rsqrtf(var + EPS_);

    float4 ga  = *(const float4*)(gg + lane * 8);
    float4 gb  = *(const float4*)(gg + lane * 8 + 4);
    float4 ba  = *(const float4*)(bb + lane * 8);
    float4 bb4 = *(const float4*)(bb + lane * 8 + 4);

    float4 r0, r1;
    r0.x = (v0.x - mean) * rstd * ga.x + ba.x;
    r0.y = (v0.y - mean) * rstd * ga.y + ba.y;
    r0.z = (v0.z - mean) * rstd * ga.z + ba.z;
    r0.w = (v0.w - mean) * rstd * ga.w + ba.w;
    r1.x = (v1.x - mean) * rstd * gb.x + bb4.x;
    r1.y = (v1.y - mean) * rstd * gb.y + bb4.y;
    r1.z = (v1.z - mean) * rstd * gb.z + bb4.z;
    r1.w = (v1.w - mean) * rstd * gb.w + bb4.w;

    float* orow = o + (size_t)row * C_ + lane * 8;
    *(float4*)orow       = r0;
    *(float4*)(orow + 4) = r1;
}

// ---------------------------------------------------------------------------
// K2: pair path. One 32-lane group per (b,i,j) row of pair_embed (P=128):
// LN over P, dot with w_pb and w_pg (H=4 heads), gate, add mask bias,
// write bias[B,H,I,J]. This kernel reads the 512 MB tensor - the roofline.
// grid: (B*I*J/8), block: 256 (4 waves, 2 rows per wave)
// ---------------------------------------------------------------------------
__global__ __launch_bounds__(256) void k_pair_bias(
    const float* __restrict__ pair, const int* __restrict__ pmask,
    const float* __restrict__ lng, const float* __restrict__ lnb,
    const float* __restrict__ wpb, const float* __restrict__ wpg,
    float* __restrict__ bias)
{
    const int tid  = threadIdx.x;
    const int wid  = tid >> 6;
    const int lane = tid & 63;
    const int half = lane >> 5;
    const int l32  = lane & 31;

    const int row = blockIdx.x * 8 + wid * 2 + half;   // [0, B*I*J)
    const int j  = row & (J_ - 1);
    const int t2 = row >> 9;           // b*I + i
    const int i  = t2 & (I_ - 1);
    const int b  = t2 >> 9;

    const float4 x = *(const float4*)(pair + (size_t)row * P_ + l32 * 4);

    float s  = x.x + x.y + x.z + x.w;
    float sq = x.x*x.x + x.y*x.y + x.z*x.z + x.w*x.w;
#pragma unroll
    for (int m = 1; m <= 16; m <<= 1) {
        s  += __shfl_xor(s, m);
        sq += __shfl_xor(sq, m);
    }
    const float mean = s * (1.0f / P_);
    const float rstd = rsqrtf(sq * (1.0f / P_) - mean * mean + EPS_);

    const float4 lg4 = *(const float4*)(lng + l32 * 4);
    const float4 lb4 = *(const float4*)(lnb + l32 * 4);
    const float z0 = (x.x - mean) * rstd * lg4.x + lb4.x;
    const float z1 = (x.y - mean) * rstd * lg4.y + lb4.y;
    const float z2 = (x.z - mean) * rstd * lg4.z + lb4.z;
    const float z3 = (x.w - mean) * rstd * lg4.w + lb4.w;

    // w_pb/w_pg are [P][H] row-major; this lane's 4 p-rows = 16 consecutive floats
    const float4 wb0 = *(const float4*)(wpb + l32 * 16);
    const float4 wb1 = *(const float4*)(wpb + l32 * 16 + 4);
    const float4 wb2 = *(const float4*)(wpb + l32 * 16 + 8);
    const float4 wb3 = *(const float4*)(wpb + l32 * 16 + 12);
    const float4 wg0 = *(const float4*)(wpg + l32 * 16);
    const float4 wg1 = *(const float4*)(wpg + l32 * 16 + 4);
    const float4 wg2 = *(const float4*)(wpg + l32 * 16 + 8);
    const float4 wg3 = *(const float4*)(wpg + l32 * 16 + 12);

    float lh0 = z0*wb0.x + z1*wb1.x + z2*wb2.x + z3*wb3.x;
    float lh1 = z0*wb0.y + z1*wb1.y + z2*wb2.y + z3*wb3.y;
    float lh2 = z0*wb0.z + z1*wb1.z + z2*wb2.z + z3*wb3.z;
    float lh3 = z0*wb0.w + z1*wb1.w + z2*wb2.w + z3*wb3.w;
    float gh0 = z0*wg0.x + z1*wg1.x + z2*wg2.x + z3*wg3.x;
    float gh1 = z0*wg0.y + z1*wg1.y + z2*wg2.y + z3*wg3.y;
    float gh2 = z0*wg0.z + z1*wg1.z + z2*wg2.z + z3*wg3.z;
    float gh3 = z0*wg0.w + z1*wg1.w + z2*wg2.w + z3*wg3.w;

#pragma unroll
    for (int m = 1; m <= 16; m <<= 1) {
        lh0 += __shfl_xor(lh0, m); lh1 += __shfl_xor(lh1, m);
        lh2 += __shfl_xor(lh2, m); lh3 += __shfl_xor(lh3, m);
        gh0 += __shfl_xor(gh0, m); gh1 += __shfl_xor(gh1, m);
        gh2 += __shfl_xor(gh2, m); gh3 += __shfl_xor(gh3, m);
    }

    if (l32 < 4) {
        const float mb = INF_ * ((float)pmask[row] - 1.0f);
        const float L = (l32 == 0) ? lh0 : (l32 == 1) ? lh1 : (l32 == 2) ? lh2 : lh3;
        const float G = (l32 == 0) ? gh0 : (l32 == 1) ? gh1 : (l32 == 2) ? gh2 : gh3;
        const float val = L * (1.0f / (1.0f + __expf(-G))) + mb;
        bias[(((size_t)(b * H_ + l32) * I_ + i) << 9) + j] = val;
    }
}

// ---------------------------------------------------------------------------
// K3: projections q,k,v,g. blockIdx.y selects the matrix. 16-row A tile in
// LDS (reads are wave-uniform -> broadcast); weights streamed from L2.
// grid: (B*I/16, 4), block: 256. Each thread: 1 col x 8 rows.
// ---------------------------------------------------------------------------
__global__ __launch_bounds__(256) void k_proj(
    const float* __restrict__ ni, const float* __restrict__ nj,
    const float* __restrict__ wq, const float* __restrict__ wk,
    const float* __restrict__ wv, const float* __restrict__ wg,
    const float* __restrict__ bg,
    float* __restrict__ q_ws, float* __restrict__ k_ws,
    float* __restrict__ v_ws, float* __restrict__ g_ws)
{
    __shared__ float s_src[16 * 512];
    const int y    = blockIdx.y;
    const int tid  = threadIdx.x;
    const int base = blockIdx.x * 16;   // row in [0, B*I)

    const float* src = (y == 0 || y == 3) ? ni : nj;
    const float* W   = (y == 0) ? wq : (y == 1) ? wk : (y == 2) ? wv : wg;

    const float* sg = src + (size_t)base * C_;
#pragma unroll
    for (int rep = 0; rep < 8; rep++) {
        const int flat = rep * 1024 + tid * 4;
        *(float4*)&s_src[flat] = *(const float4*)(sg + flat);
    }
    __syncthreads();

    const int col = tid & 127;
    const int r0  = (tid >> 7) * 8;
    float acc[8] = {0, 0, 0, 0, 0, 0, 0, 0};

#pragma unroll 4
    for (int c = 0; c < C_; c++) {
        const float w = W[c * HD_ + col];
#pragma unroll
        for (int r = 0; r < 8; r++) acc[r] += s_src[(r0 + r) * 512 + c] * w;
    }

    if (y == 3) {
        const float bgc = bg[col];
#pragma unroll
        for (int r = 0; r < 8; r++) {
            const float gv = 1.0f / (1.0f + __expf(-(acc[r] + bgc)));
            g_ws[(size_t)(base + r0 + r) * HD_ + col] = gv;
        }
    } else {
        const int b  = base >> 9;
        const int i0 = base & 511;
        const int h  = col >> 5, d = col & 31;
        const float scale = (y == 0) ? 0.17677669529663689f : 1.0f;  // 1/sqrt(32)
        float* dst = (y == 0) ? q_ws : (y == 1) ? k_ws : v_ws;
#pragma unroll
        for (int r = 0; r < 8; r++)
            dst[((size_t)(b * H_ + h) * 512 + i0 + r0 + r) * D_ + d] = acc[r] * scale;
    }
}

// ---------------------------------------------------------------------------
// K4: attention for one (b,h) and a 16-row i tile. Phase A: each thread owns
// one i-row (shared by its 16-lane group) and 32 logits in registers
// (j = l16 + 16e); q in registers; k read from L2 (64 KB per (b,h), hot).
// Softmax fully in registers via 16-lane butterflies. Phase B: PV with
// a-values from LDS (broadcast) and v from L2.
// grid: (I/16, B*H), block: 256
// ---------------------------------------------------------------------------
__global__ __launch_bounds__(256) void k_attn(
    const float* __restrict__ q_ws, const float* __restrict__ k_ws,
    const float* __restrict__ v_ws, const float* __restrict__ bias,
    float* __restrict__ o_ws)
{
    __shared__ float s_a[16 * 520];
    const int tid = threadIdx.x;
    const int bh  = blockIdx.y;          // b*H + h
    const int b   = bh >> 2, h = bh & 3;
    const int i0  = blockIdx.x * 16;
    const int i   = tid >> 4;
    const int l16 = tid & 15;

    const float* qrow = q_ws + ((size_t)bh * I_ + i0 + i) * D_;
    const float4 q0 = *(const float4*)(qrow);
    const float4 q1 = *(const float4*)(qrow + 4);
    const float4 q2 = *(const float4*)(qrow + 8);
    const float4 q3 = *(const float4*)(qrow + 12);
    const float4 q4 = *(const float4*)(qrow + 16);
    const float4 q5 = *(const float4*)(qrow + 20);
    const float4 q6 = *(const float4*)(qrow + 24);
    const float4 q7 = *(const float4*)(qrow + 28);

    float acc[32];
    const float* brow = bias + ((size_t)bh * I_ + i0 + i) * J_;
#pragma unroll
    for (int e = 0; e < 32; e++) acc[e] = brow[l16 + 16 * e];

    const float* kbase = k_ws + (size_t)bh * J_ * D_;
#pragma unroll
    for (int e = 0; e < 32; e++) {
        const float* kp = kbase + (l16 + 16 * e) * D_;
        const float4 k0 = *(const float4*)(kp);
        const float4 k1 = *(const float4*)(kp + 4);
        const float4 k2 = *(const float4*)(kp + 8);
        const float4 k3 = *(const float4*)(kp + 12);
        const float4 k4 = *(const float4*)(kp + 16);
        const float4 k5 = *(const float4*)(kp + 20);
        const float4 k6 = *(const float4*)(kp + 24);
        const float4 k7 = *(const float4*)(kp + 28);
        acc[e] += dot4(q0, k0) + dot4(q1, k1) + dot4(q2, k2) + dot4(q3, k3)
                + dot4(q4, k4) + dot4(q5, k5) + dot4(q6, k6) + dot4(q7, k7);
    }

    // softmax in registers (row spread over a 16-lane group)
    float mx = acc[0];
#pragma unroll
    for (int e = 1; e < 32; e++) mx = fmaxf(mx, acc[e]);
#pragma unroll
    for (int m = 1; m < 16; m <<= 1) mx = fmaxf(mx, __shfl_xor(mx, m));
    float sum = 0.0f;
#pragma unroll
    for (int e = 0; e < 32; e++) { acc[e] = __expf(acc[e] - mx); sum += acc[e]; }
#pragma unroll
    for (int m = 1; m < 16; m <<= 1) sum += __shfl_xor(sum, m);
#pragma unroll
    for (int e = 0; e < 32; e++) s_a[i * 520 + l16 + 16 * e] = acc[e];
    const float scale = 1.0f / sum;
    __syncthreads();

    // PV: thread = (i, d-pair). a broadcast from LDS, v from L2.
    const int dg = l16;
    const float* vbase = v_ws + (size_t)bh * J_ * D_ + 2 * dg;
    float o0 = 0.0f, o1 = 0.0f;
#pragma unroll 8
    for (int jj = 0; jj < J_; jj++) {
        const float a = s_a[i * 520 + jj];
        const float2 vv = *(const float2*)(vbase + (size_t)jj * D_);
        o0 += a * vv.x;
        o1 += a * vv.y;
    }
    float* op = o_ws + ((size_t)(b * I_ + i0 + i)) * HD_ + h * D_ + 2 * dg;
    op[0] = o0 * scale;
    op[1] = o1 * scale;
}

// ---------------------------------------------------------------------------
// K5: out = ni + ((o*g) @ wo + bo) * node_mask. 8-row tile, o*g in LDS
// (broadcast reads), wo streamed from L2. Thread = 2 cols x 8 rows.
// grid: (B*I/8), block: 256
// ---------------------------------------------------------------------------
__global__ __launch_bounds__(256) void k_out(
    const float* __restrict__ o_ws, const float* __restrict__ g_ws,
    const float* __restrict__ ni, const float* __restrict__ wo,
    const float* __restrict__ bo, const int* __restrict__ nmask,
    float* __restrict__ out)
{
    __shared__ float s_og[8 * 128];
    const int tid  = threadIdx.x;
    const int base = blockIdx.x * 8;     // row in [0, B*I)

#pragma unroll
    for (int rep = 0; rep < 4; rep++) {
        const int flat = rep * 256 + tid;
        s_og[flat] = o_ws[(size_t)base * HD_ + flat] * g_ws[(size_t)base * HD_ + flat];
    }
    __syncthreads();

    const int c0 = tid * 2;
    float a0[8] = {0, 0, 0, 0, 0, 0, 0, 0};
    float a1[8] = {0, 0, 0, 0, 0, 0, 0, 0};

#pragma unroll 4
    for (int hd = 0; hd < HD_; hd++) {
        const float2 w = *(const float2*)(wo + hd * C_ + c0);
#pragma unroll
        for (int r = 0; r < 8; r++) {
            const float v = s_og[r * 128 + hd];
            a0[r] += v * w.x;
            a1[r] += v * w.y;
        }
    }

    const float b0v = bo[c0], b1v = bo[c0 + 1];
#pragma unroll
    for (int r = 0; r < 8; r++) {
        const int row = base + r;
        const float mk = (float)nmask[row];
        const size_t off = (size_t)row * C_ + c0;
        out[off]     = ni[off]     + (a0[r] + b0v) * mk;
        out[off + 1] = ni[off + 1] + (a1[r] + b1v) * mk;
    }
}

// ---------------------------------------------------------------------------
extern "C" void kernel_launch(void* const* d_in, const int* in_sizes, int n_in,
                              void* d_out, int out_size, void* d_ws, size_t ws_size,
                              hipStream_t stream)
{
    const float* node_i = (const float*)d_in[0];
    const float* node_j = (const float*)d_in[1];
    const float* pair   = (const float*)d_in[2];
    const int*   pmask  = (const int*)d_in[3];
    const int*   nmask  = (const int*)d_in[4];
    const float* ln_i_g = (const float*)d_in[5];
    const float* ln_i_b = (const float*)d_in[6];
    const float* ln_j_g = (const float*)d_in[7];
    const float* ln_j_b = (const float*)d_in[8];
    const float* ln_p_g = (const float*)d_in[9];
    const float* ln_p_b = (const float*)d_in[10];
    const float* w_pb   = (const float*)d_in[11];
    const float* w_pg   = (const float*)d_in[12];
    const float* wq     = (const float*)d_in[13];
    const float* wk     = (const float*)d_in[14];
    const float* wv     = (const float*)d_in[15];
    const float* wg     = (const float*)d_in[16];
    const float* bg     = (const float*)d_in[17];
    const float* wo     = (const float*)d_in[18];
    const float* bo     = (const float*)d_in[19];

    float* out = (float*)d_out;
    float* ws  = (float*)d_ws;

    float* ni   = ws;                 // 1,048,576 floats
    float* nj   = ws + 1048576;       // 1,048,576
    float* bias = ws + 2097152;       // 4,194,304  [B,H,I,J]
    float* q_ws = ws + 6291456;       // 262,144    [B,H,I,D]
    float* k_ws = ws + 6553600;       // 262,144    [B,H,J,D]
    float* v_ws = ws + 6815744;       // 262,144    [B,H,J,D]
    float* g_ws = ws + 7077888;       // 262,144    [B,I,HD]
    float* o_ws = ws + 7340032;       // 262,144    [B,I,HD]

    k_ln_nodes<<<dim3(512, 2), 256, 0, stream>>>(node_i, node_j, ln_i_g, ln_i_b,
                                                 ln_j_g, ln_j_b, ni, nj);
    k_pair_bias<<<dim3(131072), 256, 0, stream>>>(pair, pmask, ln_p_g, ln_p_b,
                                                  w_pb, w_pg, bias);
    k_proj<<<dim3(128, 4), 256, 0, stream>>>(ni, nj, wq, wk, wv, wg, bg,
                                             q_ws, k_ws, v_ws, g_ws);
    k_attn<<<dim3(32, 16), 256, 0, stream>>>(q_ws, k_ws, v_ws, bias, o_ws);
    k_out<<<dim3(256), 256, 0, stream>>>(o_ws, g_ws, ni, wo, bo, nmask, out);
}